// Round 7
// baseline (110.326 us; speedup 1.0000x reference)
//
#include <hip/hip_runtime.h>
#include <cmath>

// Problem constants
#define BATCH 8
#define HF 512
#define WF 512
#define HS 256
#define WS 256
#define PLANE_S (HS * WS)   // 65536
#define PLANE_F (HF * WF)   // 262144

#define NMIND_BLOCKS 2048   // 16x16 tiles x 8 batches
#define NREG_BLOCKS  512    // 8x8 tiles x 8 batches

// mega patch geometry for a 32x32 output tile
#define IMG_R 23   // pooled img patch rows/cols (V_R + 5 halo)
#define IMG_S 24   // LDS stride
#define T_R 20     // (img - offset-boxmean)^2 patch
#define T_S 21
#define V_R 18     // variance / diff patch
#define V_S 19
#define V_PLANE (V_R * V_S)   // 342; diff = 4 pair-planes of 342 float2

// reg patch geometry for a 32x32 pooled tile
#define RP 34
#define RS 35

// ---- cross-kernel state in MODULE GLOBALS (not d_ws -> not poisoned).
// Zero-initialized at module load; tail's last block re-zeroes hist+cnt for the
// next graph iteration (safe: ticket==7 implies all 8 blocks finished reading).
__device__ unsigned g_hist[BATCH * 256];
__device__ unsigned g_cnt;
__device__ unsigned g_nmib[BATCH];
__device__ double   g_pmind[NMIND_BLOCKS];
__device__ double   g_pgrad[NREG_BLOCKS];
__device__ double   g_plap[NREG_BLOCKS];

__device__ __forceinline__ int clampi(int v, int lo, int hi) {
    return v < lo ? lo : (v > hi ? hi : v);
}

__device__ __forceinline__ int bin_of(float x) {
    float v = (x + 1.0f) * 0.5f;
    v = fminf(fmaxf(v, 0.001f), 0.999f);
    float t = v * 16.0f;            // exact (power-of-2 scale)
    float ft = floorf(t);
    int c = (int)ft + ((t > ft) ? 1 : 0);   // searchsorted-left count of grid < v
    int b = c - 1;
    return b < 0 ? 0 : (b > 15 ? 15 : b);
}

// ONE kernel, two roles by blockIdx.z:
//   z in {0,1}  : reg path  — 512 blocks (8x8 pooled tiles x 8 batches)
//   z in 2..9   : mind path — 2048 blocks (16x16 output tiles x 8 batches), b = z-2
// LDS 20144 B (<=20480) -> 8 blocks/CU. diff is PAIR-PLANAR (float2 per channel
// pair): upsample reads 16 b64/px (was 32 b32), MIND writes 4 b64 (was 8 b32).
__global__ __launch_bounds__(256, 8) void fused_main_kernel(
    const float* __restrict__ fixed, const float* __restrict__ moved,
    const float* __restrict__ flow)
{
    __shared__ __align__(16) float S[4524];
    __shared__ unsigned lh[256];
    __shared__ float red[256];
    int tid = threadIdx.x;

    if (blockIdx.z < 2) {
        // ---------------- reg path: pool(flow) -> Sobel + Laplacian partial sums
        int idx = blockIdx.z * 256 + blockIdx.y * 16 + blockIdx.x;  // 0..511
        int b = idx >> 6, t64 = idx & 63;
        int y0p = (t64 >> 3) * 32, x0p = (t64 & 7) * 32;
        float* U = S;
        float* V = S + RP * RS;
        const float* ur = flow + (size_t)(b * 2) * PLANE_F;
        const float* vr = ur + PLANE_F;
        for (int i = tid; i < RP * RP; i += 256) {
            int r = i / RP, c = i - r * RP;
            int gy = clampi(y0p - 1 + r, 0, HS - 1);
            int gx = clampi(x0p - 1 + c, 0, WS - 1);
            const float* uu = ur + (size_t)(gy * 2) * WF + (size_t)(gx * 2);
            const float* vv = vr + (size_t)(gy * 2) * WF + (size_t)(gx * 2);
            float2 u0 = *(const float2*)uu, u1 = *(const float2*)(uu + WF);
            float2 v0 = *(const float2*)vv, v1 = *(const float2*)(vv + WF);
            U[r * RS + c] = (u0.x + u0.y + u1.x + u1.y) * 0.25f;
            V[r * RS + c] = (v0.x + v0.y + v1.x + v1.y) * 0.25f;
        }
        __syncthreads();
        float g = 0.f, l = 0.f;
        for (int k = tid; k < 32 * 32; k += 256) {
            int y = k >> 5, x = k & 31;
            const float* u0 = &U[y * RS + x];
            const float* v0 = &V[y * RS + x];
            float a00 = u0[0],      a01 = u0[1],          a02 = u0[2];
            float a10 = u0[RS],     a11 = u0[RS + 1],     a12 = u0[RS + 2];
            float a20 = u0[2 * RS], a21 = u0[2 * RS + 1], a22 = u0[2 * RS + 2];
            float c00 = v0[0],      c01 = v0[1],          c02 = v0[2];
            float c10 = v0[RS],     c11 = v0[RS + 1],     c12 = v0[RS + 2];
            float c20 = v0[2 * RS], c21 = v0[2 * RS + 1], c22 = v0[2 * RS + 2];
            float gxu = (a02 - a00) + 2.f * (a12 - a10) + (a22 - a20);
            float gyu = (a20 - a00) + 2.f * (a21 - a01) + (a22 - a02);
            float gxv = (c02 - c00) + 2.f * (c12 - c10) + (c22 - c20);
            float gyv = (c20 - c00) + 2.f * (c21 - c01) + (c22 - c02);
            float lpu = a01 + a10 - 4.f * a11 + a12 + a21;
            float lpv = c01 + c10 - 4.f * c11 + c12 + c21;
            float grad = gxu * gxu + gyu * gyu + gxv * gxv + gyv * gyv;
            float lap = lpu * lpu + lpv * lpv;
            g += fminf(grad, 100.f);
            l += fminf(lap, 100.f);
        }
        red[tid] = g;
        __syncthreads();
        for (int s = 128; s > 0; s >>= 1) { if (tid < s) red[tid] += red[tid + s]; __syncthreads(); }
        if (tid == 0) g_pgrad[b * 64 + t64] = (double)red[0];
        __syncthreads();
        red[tid] = l;
        __syncthreads();
        for (int s = 128; s > 0; s >>= 1) { if (tid < s) red[tid] += red[tid + s]; __syncthreads(); }
        if (tid == 0) g_plap[b * 64 + t64] = (double)red[0];
        return;
    }

    // ---------------- mind path
    const float FS = (float)(255.0 / 511.0);
    int tx = blockIdx.x, ty = blockIdx.y, b = blockIdx.z - 2;
    int Xb = tx * 32, Yb = ty * 32;
    int dbx = (int)((float)Xb * FS);   // min x0 over the tile (fp32 multiply is monotone)
    int dby = (int)((float)Yb * FS);
    int ibx = dbx - 3, iby = dby - 3;  // pooled img patch base

    float* imgF = S;                        // 23*24 = 552
    float* imgM = S + IMG_R * IMG_S;        // 552
    float* varF = S + 2 * IMG_R * IMG_S;    // 18*19 = 342
    float* varM = varF + V_R * V_S;         // 342
    float* diff = varM + V_R * V_S;         // 2736 floats = 4 pair-planes x 342 float2
    // Aliases inside the (currently dead) diff region:
    float* tF   = diff;                     // 20*21 = 420
    float* tM   = diff + 420;               // 420
    float* rsF  = diff + 840;               // 22*20 = 440 (img row-sums)
    float* rsM  = diff + 1280;              // 440
    float* vsF  = diff + 840;               // 20*18 = 360 (t row-sums; rs dead)
    float* vsM  = diff + 1200;              // 360

    lh[tid] = 0u;
    __syncthreads();

    // ---- stage pooled F/M patches in COLUMN PAIRS (b64 LDS writes) + histogram
    const float* fb = fixed + (size_t)b * PLANE_F;
    const float* mb = moved + (size_t)b * PLANE_F;
    int oy0 = ty * 16, ox0 = tx * 16;   // owned pooled box for the histogram
    for (int i = tid; i < IMG_R * 12; i += 256) {
        int r = i / 12, pc = i - r * 12;
        int c0 = pc * 2;                 // 0,2,...,22 (22 is a singleton)
        int gy = iby + r;
        int cy = clampi(gy, 0, HS - 1);
        const float* frow = fb + (size_t)(cy * 2) * WF;
        const float* mrow = mb + (size_t)(cy * 2) * WF;
        bool rowOwn = (unsigned)(gy - oy0) < 16u;

        int gx0 = ibx + c0;
        int cx0 = clampi(gx0, 0, WS - 1);
        float2 f0 = *(const float2*)(frow + cx0 * 2);
        float2 f1 = *(const float2*)(frow + WF + cx0 * 2);
        float2 m0 = *(const float2*)(mrow + cx0 * 2);
        float2 m1 = *(const float2*)(mrow + WF + cx0 * 2);
        float pF0 = (f0.x + f0.y + f1.x + f1.y) * 0.25f;
        float pM0 = (m0.x + m0.y + m1.x + m1.y) * 0.25f;
        if (rowOwn && (unsigned)(gx0 - ox0) < 16u)
            atomicAdd(&lh[bin_of(f0.x) * 16 + bin_of(m0.x)], 1u);

        if (c0 + 1 < IMG_R) {
            int gx1 = gx0 + 1;
            int cx1 = clampi(gx1, 0, WS - 1);
            float2 f0b = *(const float2*)(frow + cx1 * 2);
            float2 f1b = *(const float2*)(frow + WF + cx1 * 2);
            float2 m0b = *(const float2*)(mrow + cx1 * 2);
            float2 m1b = *(const float2*)(mrow + WF + cx1 * 2);
            float pF1 = (f0b.x + f0b.y + f1b.x + f1b.y) * 0.25f;
            float pM1 = (m0b.x + m0b.y + m1b.x + m1b.y) * 0.25f;
            if (rowOwn && (unsigned)(gx1 - ox0) < 16u)
                atomicAdd(&lh[bin_of(f0b.x) * 16 + bin_of(m0b.x)], 1u);
            *(float2*)&imgF[r * IMG_S + c0] = make_float2(pF0, pF1);   // even idx -> 8B aligned
            *(float2*)&imgM[r * IMG_S + c0] = make_float2(pM0, pM1);
        } else {
            imgF[r * IMG_S + c0] = pF0;
            imgM[r * IMG_S + c0] = pM0;
        }
    }
    __syncthreads();
    // accumulate non-zero bins into the per-batch global histogram (integer = exact)
    if (lh[tid]) atomicAdd(&g_hist[b * 256 + tid], lh[tid]);

    const float NINTH = 1.0f / 9.0f;

    // ---- 2a: img row-sums  rs[rr][c] = img[rr][c] + img[rr][c+1] + img[rr][c+2]
    for (int i = tid; i < 22 * 20; i += 256) {
        int rr = i / 20, c = i - rr * 20;
        const float* pF = &imgF[rr * IMG_S + c];
        const float* pM = &imgM[rr * IMG_S + c];
        rsF[i] = (pF[0] + pF[1]) + pF[2];
        rsM[i] = (pM[0] + pM[1]) + pM[2];
    }
    __syncthreads();

    // ---- 2b: t = (img[r+2][c+2] - boxmean)^2 via column sum of rs
    for (int i = tid; i < T_R * T_R; i += 256) {
        int r = i / T_R, c = i - r * T_R;
        float sF = (rsF[r * 20 + c] + rsF[(r + 1) * 20 + c]) + rsF[(r + 2) * 20 + c];
        float sM = (rsM[r * 20 + c] + rsM[(r + 1) * 20 + c]) + rsM[(r + 2) * 20 + c];
        float dF = imgF[(r + 2) * IMG_S + c + 2] - sF * NINTH;
        float dM = imgM[(r + 2) * IMG_S + c + 2] - sM * NINTH;
        tF[r * T_S + c] = dF * dF;
        tM[r * T_S + c] = dM * dM;
    }
    __syncthreads();

    // ---- 3a: t row-sums
    for (int i = tid; i < 20 * 18; i += 256) {
        int rr = i / 18, c = i - rr * 18;
        const float* pF = &tF[rr * T_S + c];
        const float* pM = &tM[rr * T_S + c];
        vsF[i] = (pF[0] + pF[1]) + pF[2];
        vsM[i] = (pM[0] + pM[1]) + pM[2];
    }
    __syncthreads();

    // ---- 3b: var = max(colsum(vs)/9, 1e-4)
    for (int i = tid; i < V_R * V_R; i += 256) {
        int r = i / V_R, c = i - r * V_R;
        float sF = (vsF[r * 18 + c] + vsF[(r + 1) * 18 + c]) + vsF[(r + 2) * 18 + c];
        float sM = (vsM[r * 18 + c] + vsM[(r + 1) * 18 + c]) + vsM[(r + 2) * 18 + c];
        varF[r * V_S + c] = fmaxf(sF * NINTH, 1e-4f);
        varM[r * V_S + c] = fmaxf(sM * NINTH, 1e-4f);
    }
    __syncthreads();

    // ---- MIND + diff (overwrites dead t/rs/vs), PAIR-PLANAR b64 writes
    float2* d2w = (float2*)diff;
    for (int i = tid; i < V_R * V_R; i += 256) {
        int r = i / V_R, c = i - r * V_R;
        float cF = imgF[(r + 3) * IMG_S + c + 3];
        float cM = imgM[(r + 3) * IMG_S + c + 3];
        float dF2 = 2.f * varF[r * V_S + c] + 1e-6f;
        float dM2 = 2.f * varM[r * V_S + c] + 1e-6f;
        float invF = 1.0f / dF2;
        float invM = 1.0f / dM2;
        float eF[8], eM[8];
        float sF = 0.f, sM = 0.f;
        int ch = 0;
        #pragma unroll
        for (int ii = -1; ii <= 1; ii++) {
            #pragma unroll
            for (int jj = -1; jj <= 1; jj++) {
                if (ii == 0 && jj == 0) continue;
                float aF = cF - imgF[(r + 3 + 2 * jj) * IMG_S + (c + 3 + 2 * ii)];
                float aM = cM - imgM[(r + 3 + 2 * jj) * IMG_S + (c + 3 + 2 * ii)];
                float qF = fminf(aF * aF * invF, 50.f);
                float qM = fminf(aM * aM * invM, 50.f);
                float vF_ = __expf(-qF), vM_ = __expf(-qM);
                eF[ch] = vF_; eM[ch] = vM_;
                sF += vF_; sM += vM_;
                ch++;
            }
        }
        float wF = 1.f / (sF + 1e-8f);
        float wM = 1.f / (sM + 1e-8f);
        int pix = r * V_S + c;
        #pragma unroll
        for (int q2 = 0; q2 < 4; q2++)
            d2w[q2 * V_PLANE + pix] = make_float2(eF[2 * q2] * wF - eM[2 * q2] * wM,
                                                  eF[2 * q2 + 1] * wF - eM[2 * q2 + 1] * wM);
    }
    __syncthreads();

    // ---- bilinear upsample + sum|.|: 16 b64 reads/px, 4 independent px unrolled
    float local = 0.f;
    const float2* d2 = (const float2*)diff;
    #pragma unroll
    for (int kk = 0; kk < 4; kk++) {
        int k = tid + kk * 256;           // 4*256 = 1024 exactly
        int dy = k >> 5, dx = k & 31;
        float py = (float)(Yb + dy) * FS;
        int y0 = (int)py; if (y0 > HS - 2) y0 = HS - 2;
        float fy = py - (float)y0;
        float px = (float)(Xb + dx) * FS;
        int x0 = (int)px; if (x0 > WS - 2) x0 = WS - 2;
        float fx = px - (float)x0;
        int i00 = (y0 - dby) * V_S + (x0 - dbx);
        float wy0 = 1.f - fy, wx0 = 1.f - fx;
        #pragma unroll
        for (int q2 = 0; q2 < 4; q2++) {
            float2 v00 = d2[q2 * V_PLANE + i00];
            float2 v01 = d2[q2 * V_PLANE + i00 + 1];
            float2 v10 = d2[q2 * V_PLANE + i00 + V_S];
            float2 v11 = d2[q2 * V_PLANE + i00 + V_S + 1];
            float a0 = v00.x * wy0 + v10.x * fy;
            float c0 = v01.x * wy0 + v11.x * fy;
            local += fabsf(a0 * wx0 + c0 * fx);
            float a1 = v00.y * wy0 + v10.y * fy;
            float c1 = v01.y * wy0 + v11.y * fy;
            local += fabsf(a1 * wx0 + c1 * fx);
        }
    }
    red[tid] = local;
    __syncthreads();
    for (int s = 128; s > 0; s >>= 1) { if (tid < s) red[tid] += red[tid + s]; __syncthreads(); }
    if (tid == 0) g_pmind[b * 256 + ty * 16 + tx] = (double)red[0];
}

// 8 parallel blocks: block b computes nmi(b); last finisher (ticket) runs the
// final partial-sum reduction, writes out, and RE-ZEROES hist+cnt for the next
// graph iteration (all 8 blocks have finished their hist reads by then).
__global__ void tail_kernel(float* __restrict__ out) {
    int b = blockIdx.x;
    int t = threadIdx.x;  // 256
    __shared__ float p[256];
    __shared__ float xh[16], yh[16];
    __shared__ float redf[256];
    __shared__ double red[256];
    __shared__ unsigned ticket;

    // ---- nmi(b)
    unsigned hv = g_hist[b * 256 + t];
    float pv = (float)hv / 65536.0f;  // sum+1e-10 == 65536 in fp32
    p[t] = pv;
    __syncthreads();
    if (t < 16) {
        float s = 0.f;
        for (int j = 0; j < 16; j++) s += p[t * 16 + j];
        xh[t] = s;
    } else if (t < 32) {
        int j = t - 16;
        float s = 0.f;
        for (int i = 0; i < 16; i++) s += p[i * 16 + j];
        yh[j] = s;
    }
    __syncthreads();
    const float eps = 1e-5f;
    int i = t >> 4, j = t & 15;
    float h = pv + eps;
    float mi_term = h * (logf(h) - logf((xh[i] + eps) * (yh[j] + eps)));
    redf[t] = mi_term;
    __syncthreads();
    for (int s = 128; s > 0; s >>= 1) { if (t < s) redf[t] += redf[t + s]; __syncthreads(); }
    float mi = redf[0];
    __syncthreads();
    float e_term = 0.f;
    if (t < 16) { float xe = xh[t] + eps; e_term = -xe * logf(xe); }
    else if (t < 32) { float ye = yh[t - 16] + eps; e_term = -ye * logf(ye); }
    redf[t] = e_term;
    __syncthreads();
    for (int s = 128; s > 0; s >>= 1) { if (t < s) redf[t] += redf[t + s]; __syncthreads(); }
    if (t == 0) {
        float se = redf[0];  // hx + hy
        float nmi = (se < 1e-10f) ? 0.f : 2.f * mi / se;
        nmi = fminf(fmaxf(nmi, -1.f), 1.f);
        atomicExch(&g_nmib[b], __float_as_uint(nmi));
        ticket = atomicAdd(&g_cnt, 1u);
    }
    __syncthreads();
    if (ticket != BATCH - 1) return;

    // ---- last block: final reduction (partials plain-stored by previous kernel
    // -> visible across the kernel boundary; nmi read via device-scope atomics)
    double sm = 0.0;
    for (int i2 = t; i2 < NMIND_BLOCKS; i2 += 256) sm += g_pmind[i2];
    double sg = 0.0, sl = 0.0;
    for (int i2 = t; i2 < NREG_BLOCKS; i2 += 256) { sg += g_pgrad[i2]; sl += g_plap[i2]; }
    red[t] = sm;
    __syncthreads();
    for (int s = 128; s > 0; s >>= 1) { if (t < s) red[t] += red[t + s]; __syncthreads(); }
    double mind_sum = red[0];
    __syncthreads();
    red[t] = sg;
    __syncthreads();
    for (int s = 128; s > 0; s >>= 1) { if (t < s) red[t] += red[t + s]; __syncthreads(); }
    double grad_sum = red[0];
    __syncthreads();
    red[t] = sl;
    __syncthreads();
    for (int s = 128; s > 0; s >>= 1) { if (t < s) red[t] += red[t + s]; __syncthreads(); }
    double lap_sum = red[0];
    if (t == 0) {
        float s = 0.f;
        for (int bb = 0; bb < BATCH; bb++) {
            unsigned u = atomicOr(&g_nmib[bb], 0u);
            s += __uint_as_float(u);
        }
        s /= (float)BATCH;
        s = fminf(fmaxf(s, -1.f), 1.f);
        double mi_loss = -(double)s;
        double mind_mean = mind_sum / (64.0 * (double)PLANE_F);
        double reg = grad_sum / (double)(BATCH * PLANE_S) + lap_sum / (double)(BATCH * PLANE_S);
        out[0] = (float)(mi_loss + 5.0 * mind_mean + 0.1 * reg);
    }
    // ---- re-arm for the next graph iteration (kernel boundary publishes these)
    for (int i2 = t; i2 < BATCH * 256; i2 += 256) g_hist[i2] = 0u;
    if (t == 0) g_cnt = 0u;
}

extern "C" void kernel_launch(void* const* d_in, const int* in_sizes, int n_in,
                              void* d_out, int out_size, void* d_ws, size_t ws_size,
                              hipStream_t stream) {
    const float* fixed = (const float*)d_in[0];
    const float* moved = (const float*)d_in[1];
    const float* flow  = (const float*)d_in[2];
    float* out = (float*)d_out;
    (void)d_ws; (void)ws_size;

    // z-slices 0,1 = reg; z 2..9 = mind (b = z-2)
    fused_main_kernel<<<dim3(16, 16, 10), 256, 0, stream>>>(fixed, moved, flow);
    tail_kernel<<<dim3(BATCH), 256, 0, stream>>>(out);
}

// Round 8
// 107.125 us; speedup vs baseline: 1.0299x; 1.0299x over previous
//
#include <hip/hip_runtime.h>
#include <cmath>

// Problem constants
#define BATCH 8
#define HF 512
#define WF 512
#define HS 256
#define WS 256
#define PLANE_S (HS * WS)   // 65536
#define PLANE_F (HF * WF)   // 262144

#define NMIND_BLOCKS 2048   // 16x16 tiles x 8 batches
#define NREG_BLOCKS  512    // 8x8 tiles x 8 batches

// Workspace layout (bytes).
// hist + cnt are atomically accumulated (zeroed by init_kernel);
// partial arrays are fully written before read (no init needed).
#define OFF_HIST  0                              // 8*256 u32 = 8 KB
#define OFF_CNT   (8 * 256 * 4)                  // 1 u32 ticket counter
#define OFF_NMIB  (OFF_CNT + 4)                  // 8 u32 (nmi bits, atomic transport)
#define OFF_PMIND 8704                           // 2048 doubles
#define OFF_PGRAD (OFF_PMIND + NMIND_BLOCKS * 8)
#define OFF_PLAP  (OFF_PGRAD + NREG_BLOCKS * 8)

// mega patch geometry for a 32x32 output tile
#define IMG_R 23   // pooled img patch rows/cols (V_R + 5 halo)
#define IMG_S 24   // LDS stride
#define T_R 20     // (img - offset-boxmean)^2 patch
#define T_S 21
#define V_R 18     // variance / diff patch
#define V_S 19
#define V_PLANE (V_R * V_S)   // 342; diff = 4 pair-planes of 342 float2

// reg patch geometry for a 32x32 pooled tile
#define RP 34
#define RS 35

__device__ __forceinline__ int clampi(int v, int lo, int hi) {
    return v < lo ? lo : (v > hi ? hi : v);
}

__device__ __forceinline__ int bin_of(float x) {
    float v = (x + 1.0f) * 0.5f;
    v = fminf(fmaxf(v, 0.001f), 0.999f);
    float t = v * 16.0f;            // exact (power-of-2 scale)
    float ft = floorf(t);
    int c = (int)ft + ((t > ft) ? 1 : 0);   // searchsorted-left count of grid < v
    int b = c - 1;
    return b < 0 ? 0 : (b > 15 ? 15 : b);
}

// zero the 8x256 global histogram + ticket counter (workspace is poisoned per iteration)
__global__ void init_kernel(unsigned* __restrict__ hist, unsigned* __restrict__ cnt) {
    int t = threadIdx.x;
    for (int i = t; i < BATCH * 256; i += 256) hist[i] = 0u;
    if (t == 0) cnt[0] = 0u;
}

// ONE kernel, two roles by blockIdx.z:
//   z in {0,1}  : reg path  — 512 blocks (8x8 pooled tiles x 8 batches)
//   z in 2..9   : mind path — 2048 blocks (16x16 output tiles x 8 batches), b = z-2
// LDS 20144 B (<=20480) -> 8 blocks/CU = 32 waves/CU.
// Reductions are wave-shuffle based (1 barrier instead of 8); diff is PAIR-PLANAR
// float2 (b64 LDS ops, 2-way bank aliasing = free per m136).
__global__ __launch_bounds__(256, 8) void fused_main_kernel(
    const float* __restrict__ fixed, const float* __restrict__ moved,
    const float* __restrict__ flow,
    unsigned* __restrict__ hist, double* __restrict__ pmind,
    double* __restrict__ pgrad, double* __restrict__ plap)
{
    __shared__ __align__(16) float S[4524];
    __shared__ unsigned lh[256];
    __shared__ float red[256];
    int tid = threadIdx.x;

    if (blockIdx.z < 2) {
        // ---------------- reg path: pool(flow) -> Sobel + Laplacian partial sums
        int idx = blockIdx.z * 256 + blockIdx.y * 16 + blockIdx.x;  // 0..511
        int b = idx >> 6, t64 = idx & 63;
        int y0p = (t64 >> 3) * 32, x0p = (t64 & 7) * 32;
        float* U = S;
        float* V = S + RP * RS;
        const float* ur = flow + (size_t)(b * 2) * PLANE_F;
        const float* vr = ur + PLANE_F;
        for (int i = tid; i < RP * RP; i += 256) {
            int r = i / RP, c = i - r * RP;
            int gy = clampi(y0p - 1 + r, 0, HS - 1);
            int gx = clampi(x0p - 1 + c, 0, WS - 1);
            const float* uu = ur + (size_t)(gy * 2) * WF + (size_t)(gx * 2);
            const float* vv = vr + (size_t)(gy * 2) * WF + (size_t)(gx * 2);
            float2 u0 = *(const float2*)uu, u1 = *(const float2*)(uu + WF);
            float2 v0 = *(const float2*)vv, v1 = *(const float2*)(vv + WF);
            U[r * RS + c] = (u0.x + u0.y + u1.x + u1.y) * 0.25f;
            V[r * RS + c] = (v0.x + v0.y + v1.x + v1.y) * 0.25f;
        }
        __syncthreads();
        float g = 0.f, l = 0.f;
        for (int k = tid; k < 32 * 32; k += 256) {
            int y = k >> 5, x = k & 31;
            const float* u0 = &U[y * RS + x];
            const float* v0 = &V[y * RS + x];
            float a00 = u0[0],      a01 = u0[1],          a02 = u0[2];
            float a10 = u0[RS],     a11 = u0[RS + 1],     a12 = u0[RS + 2];
            float a20 = u0[2 * RS], a21 = u0[2 * RS + 1], a22 = u0[2 * RS + 2];
            float c00 = v0[0],      c01 = v0[1],          c02 = v0[2];
            float c10 = v0[RS],     c11 = v0[RS + 1],     c12 = v0[RS + 2];
            float c20 = v0[2 * RS], c21 = v0[2 * RS + 1], c22 = v0[2 * RS + 2];
            float gxu = (a02 - a00) + 2.f * (a12 - a10) + (a22 - a20);
            float gyu = (a20 - a00) + 2.f * (a21 - a01) + (a22 - a02);
            float gxv = (c02 - c00) + 2.f * (c12 - c10) + (c22 - c20);
            float gyv = (c20 - c00) + 2.f * (c21 - c01) + (c22 - c02);
            float lpu = a01 + a10 - 4.f * a11 + a12 + a21;
            float lpv = c01 + c10 - 4.f * c11 + c12 + c21;
            float grad = gxu * gxu + gyu * gyu + gxv * gxv + gyv * gyv;
            float lap = lpu * lpu + lpv * lpv;
            g += fminf(grad, 100.f);
            l += fminf(lap, 100.f);
        }
        // combined wave-shuffle reduction for g and l: ONE barrier total
        #pragma unroll
        for (int off = 32; off; off >>= 1) {
            g += __shfl_down(g, off);
            l += __shfl_down(l, off);
        }
        if ((tid & 63) == 0) { red[tid >> 6] = g; red[4 + (tid >> 6)] = l; }
        __syncthreads();
        if (tid == 0) {
            pgrad[b * 64 + t64] = (double)(((red[0] + red[1]) + red[2]) + red[3]);
            plap[b * 64 + t64]  = (double)(((red[4] + red[5]) + red[6]) + red[7]);
        }
        return;
    }

    // ---------------- mind path: pool -> patchmean -> variance -> MIND -> diff ->
    // bilinear upsample -> sum|.| + joint histogram of the ::2,::2 raw samples.
    const float FS = (float)(255.0 / 511.0);
    int tx = blockIdx.x, ty = blockIdx.y, b = blockIdx.z - 2;
    int Xb = tx * 32, Yb = ty * 32;
    int dbx = (int)((float)Xb * FS);   // min x0 over the tile (fp32 multiply is monotone)
    int dby = (int)((float)Yb * FS);
    int ibx = dbx - 3, iby = dby - 3;  // pooled img patch base

    float* imgF = S;                        // 23*24 = 552
    float* imgM = S + IMG_R * IMG_S;        // 552
    float* varF = S + 2 * IMG_R * IMG_S;    // 18*19 = 342
    float* varM = varF + V_R * V_S;         // 342
    float* diff = varM + V_R * V_S;         // 2736 floats = 4 pair-planes x 342 float2
    // Aliases inside the (currently dead) diff region:
    float* tF   = diff;                     // 20*21 = 420
    float* tM   = diff + 420;               // 420
    float* rsF  = diff + 840;               // 22*20 = 440 (img row-sums)
    float* rsM  = diff + 1280;              // 440
    float* vsF  = diff + 840;               // 20*18 = 360 (t row-sums; rs dead)
    float* vsM  = diff + 1200;              // 360

    lh[tid] = 0u;
    __syncthreads();

    // ---- stage pooled F/M patches (clamp-at-staging = edge-pad semantics) + histogram
    const float* fb = fixed + (size_t)b * PLANE_F;
    const float* mb = moved + (size_t)b * PLANE_F;
    int oy0 = ty * 16, ox0 = tx * 16;   // owned pooled box for the histogram (exact cover)
    for (int i = tid; i < IMG_R * IMG_R; i += 256) {
        int r = i / IMG_R, c = i - r * IMG_R;
        int gy = iby + r, gx = ibx + c;
        int cy = clampi(gy, 0, HS - 1), cx = clampi(gx, 0, WS - 1);
        const float* fp = fb + (size_t)(cy * 2) * WF + (size_t)(cx * 2);
        const float* mp = mb + (size_t)(cy * 2) * WF + (size_t)(cx * 2);
        float2 f0 = *(const float2*)fp;
        float2 f1 = *(const float2*)(fp + WF);
        float2 m0 = *(const float2*)mp;
        float2 m1 = *(const float2*)(mp + WF);
        imgF[r * IMG_S + c] = (f0.x + f0.y + f1.x + f1.y) * 0.25f;
        imgM[r * IMG_S + c] = (m0.x + m0.y + m1.x + m1.y) * 0.25f;
        // ::2,::2 histogram sample = top-left raw pixel of the pool window
        if ((unsigned)(gy - oy0) < 16u && (unsigned)(gx - ox0) < 16u) {
            atomicAdd(&lh[bin_of(f0.x) * 16 + bin_of(m0.x)], 1u);
        }
    }
    __syncthreads();
    // accumulate non-zero bins into the per-batch global histogram (integer = exact)
    if (lh[tid]) atomicAdd(&hist[b * 256 + tid], lh[tid]);

    const float NINTH = 1.0f / 9.0f;

    // ---- 2a: img row-sums  rs[rr][c] = img[rr][c] + img[rr][c+1] + img[rr][c+2]
    for (int i = tid; i < 22 * 20; i += 256) {
        int rr = i / 20, c = i - rr * 20;
        const float* pF = &imgF[rr * IMG_S + c];
        const float* pM = &imgM[rr * IMG_S + c];
        rsF[i] = (pF[0] + pF[1]) + pF[2];
        rsM[i] = (pM[0] + pM[1]) + pM[2];
    }
    __syncthreads();

    // ---- 2b: t = (img[r+2][c+2] - boxmean)^2 via column sum of rs
    for (int i = tid; i < T_R * T_R; i += 256) {
        int r = i / T_R, c = i - r * T_R;
        float sF = (rsF[r * 20 + c] + rsF[(r + 1) * 20 + c]) + rsF[(r + 2) * 20 + c];
        float sM = (rsM[r * 20 + c] + rsM[(r + 1) * 20 + c]) + rsM[(r + 2) * 20 + c];
        float dF = imgF[(r + 2) * IMG_S + c + 2] - sF * NINTH;
        float dM = imgM[(r + 2) * IMG_S + c + 2] - sM * NINTH;
        tF[r * T_S + c] = dF * dF;
        tM[r * T_S + c] = dM * dM;
    }
    __syncthreads();

    // ---- 3a: t row-sums
    for (int i = tid; i < 20 * 18; i += 256) {
        int rr = i / 18, c = i - rr * 18;
        const float* pF = &tF[rr * T_S + c];
        const float* pM = &tM[rr * T_S + c];
        vsF[i] = (pF[0] + pF[1]) + pF[2];
        vsM[i] = (pM[0] + pM[1]) + pM[2];
    }
    __syncthreads();

    // ---- 3b: var = max(colsum(vs)/9, 1e-4)
    for (int i = tid; i < V_R * V_R; i += 256) {
        int r = i / V_R, c = i - r * V_R;
        float sF = (vsF[r * 18 + c] + vsF[(r + 1) * 18 + c]) + vsF[(r + 2) * 18 + c];
        float sM = (vsM[r * 18 + c] + vsM[(r + 1) * 18 + c]) + vsM[(r + 2) * 18 + c];
        varF[r * V_S + c] = fmaxf(sF * NINTH, 1e-4f);
        varM[r * V_S + c] = fmaxf(sM * NINTH, 1e-4f);
    }
    __syncthreads();

    // ---- MIND + diff (overwrites dead t/rs/vs), PAIR-PLANAR b64 writes
    float2* d2w = (float2*)diff;
    for (int i = tid; i < V_R * V_R; i += 256) {
        int r = i / V_R, c = i - r * V_R;
        float cF = imgF[(r + 3) * IMG_S + c + 3];
        float cM = imgM[(r + 3) * IMG_S + c + 3];
        float dF2 = 2.f * varF[r * V_S + c] + 1e-6f;
        float dM2 = 2.f * varM[r * V_S + c] + 1e-6f;
        float invF = 1.0f / dF2;           // hoisted reciprocal
        float invM = 1.0f / dM2;
        float eF[8], eM[8];
        float sF = 0.f, sM = 0.f;
        int ch = 0;
        #pragma unroll
        for (int ii = -1; ii <= 1; ii++) {
            #pragma unroll
            for (int jj = -1; jj <= 1; jj++) {
                if (ii == 0 && jj == 0) continue;
                float aF = cF - imgF[(r + 3 + 2 * jj) * IMG_S + (c + 3 + 2 * ii)];
                float aM = cM - imgM[(r + 3 + 2 * jj) * IMG_S + (c + 3 + 2 * ii)];
                float qF = fminf(aF * aF * invF, 50.f);
                float qM = fminf(aM * aM * invM, 50.f);
                float vF_ = __expf(-qF), vM_ = __expf(-qM);   // v_exp_f32 fast path
                eF[ch] = vF_; eM[ch] = vM_;
                sF += vF_; sM += vM_;
                ch++;
            }
        }
        float wF = 1.f / (sF + 1e-8f);
        float wM = 1.f / (sM + 1e-8f);
        int pix = r * V_S + c;
        #pragma unroll
        for (int q2 = 0; q2 < 4; q2++)
            d2w[q2 * V_PLANE + pix] = make_float2(eF[2 * q2] * wF - eM[2 * q2] * wM,
                                                  eF[2 * q2 + 1] * wF - eM[2 * q2 + 1] * wM);
    }
    __syncthreads();

    // ---- bilinear upsample + sum|.|: 16 b64 reads/px (pair-planar), looped
    float local = 0.f;
    const float2* d2 = (const float2*)diff;
    for (int k = tid; k < 32 * 32; k += 256) {
        int dy = k >> 5, dx = k & 31;
        float py = (float)(Yb + dy) * FS;
        int y0 = (int)py; if (y0 > HS - 2) y0 = HS - 2;
        float fy = py - (float)y0;
        float px = (float)(Xb + dx) * FS;
        int x0 = (int)px; if (x0 > HS - 2) x0 = x0;   // no-op to keep structure clear
        if (x0 > WS - 2) x0 = WS - 2;
        float fx = px - (float)x0;
        int i00 = (y0 - dby) * V_S + (x0 - dbx);
        float wy0 = 1.f - fy, wx0 = 1.f - fx;
        #pragma unroll
        for (int q2 = 0; q2 < 4; q2++) {
            float2 v00 = d2[q2 * V_PLANE + i00];
            float2 v01 = d2[q2 * V_PLANE + i00 + 1];
            float2 v10 = d2[q2 * V_PLANE + i00 + V_S];
            float2 v11 = d2[q2 * V_PLANE + i00 + V_S + 1];
            float a0 = v00.x * wy0 + v10.x * fy;
            float c0 = v01.x * wy0 + v11.x * fy;
            local += fabsf(a0 * wx0 + c0 * fx);
            float a1 = v00.y * wy0 + v10.y * fy;
            float c1 = v01.y * wy0 + v11.y * fy;
            local += fabsf(a1 * wx0 + c1 * fx);
        }
    }
    // wave-shuffle reduction: 1 barrier instead of 8
    #pragma unroll
    for (int off = 32; off; off >>= 1) local += __shfl_down(local, off);
    if ((tid & 63) == 0) red[tid >> 6] = local;
    __syncthreads();
    if (tid == 0)
        pmind[b * 256 + ty * 16 + tx] = (double)(((red[0] + red[1]) + red[2]) + red[3]);
}

// 8 parallel blocks: block b computes nmi(b) from the tiny 256-bin histogram and
// publishes it via device-scope atomics; the LAST finishing block (ticket) also
// runs the final partial-sum reduction.
__global__ void tail_kernel(const unsigned* __restrict__ hist,
                            unsigned* __restrict__ cnt, unsigned* __restrict__ nmib,
                            const double* __restrict__ pmind,
                            const double* __restrict__ pgrad, const double* __restrict__ plap,
                            float* __restrict__ out) {
    int b = blockIdx.x;
    int t = threadIdx.x;  // 256
    __shared__ float p[256];
    __shared__ float xh[16], yh[16];
    __shared__ float redf[256];
    __shared__ double red[256];
    __shared__ unsigned ticket;

    // ---- nmi(b): one load per thread, then LDS reductions
    unsigned hv = hist[b * 256 + t];
    float pv = (float)hv / 65536.0f;  // sum+1e-10 == 65536 in fp32
    p[t] = pv;
    __syncthreads();
    if (t < 16) {
        float s = 0.f;
        for (int j = 0; j < 16; j++) s += p[t * 16 + j];
        xh[t] = s;
    } else if (t < 32) {
        int j = t - 16;
        float s = 0.f;
        for (int i = 0; i < 16; i++) s += p[i * 16 + j];
        yh[j] = s;
    }
    __syncthreads();
    const float eps = 1e-5f;
    int i = t >> 4, j = t & 15;
    float h = pv + eps;
    float mi_term = h * (logf(h) - logf((xh[i] + eps) * (yh[j] + eps)));
    redf[t] = mi_term;
    __syncthreads();
    for (int s = 128; s > 0; s >>= 1) { if (t < s) redf[t] += redf[t + s]; __syncthreads(); }
    float mi = redf[0];
    __syncthreads();
    float e_term = 0.f;
    if (t < 16) { float xe = xh[t] + eps; e_term = -xe * logf(xe); }
    else if (t < 32) { float ye = yh[t - 16] + eps; e_term = -ye * logf(ye); }
    redf[t] = e_term;
    __syncthreads();
    for (int s = 128; s > 0; s >>= 1) { if (t < s) redf[t] += redf[t + s]; __syncthreads(); }
    if (t == 0) {
        float se = redf[0];  // hx + hy
        float nmi = (se < 1e-10f) ? 0.f : 2.f * mi / se;
        nmi = fminf(fmaxf(nmi, -1.f), 1.f);
        atomicExch(&nmib[b], __float_as_uint(nmi));
        ticket = atomicAdd(cnt, 1u);
    }
    __syncthreads();
    if (ticket != BATCH - 1) return;

    // ---- last block: final reduction over all partials (written by the previous
    // kernel -> visible across the kernel boundary; nmi values read via atomics)
    double sm = 0.0;
    for (int i2 = t; i2 < NMIND_BLOCKS; i2 += 256) sm += pmind[i2];
    double sg = 0.0, sl = 0.0;
    for (int i2 = t; i2 < NREG_BLOCKS; i2 += 256) { sg += pgrad[i2]; sl += plap[i2]; }
    red[t] = sm;
    __syncthreads();
    for (int s = 128; s > 0; s >>= 1) { if (t < s) red[t] += red[t + s]; __syncthreads(); }
    double mind_sum = red[0];
    __syncthreads();
    red[t] = sg;
    __syncthreads();
    for (int s = 128; s > 0; s >>= 1) { if (t < s) red[t] += red[t + s]; __syncthreads(); }
    double grad_sum = red[0];
    __syncthreads();
    red[t] = sl;
    __syncthreads();
    for (int s = 128; s > 0; s >>= 1) { if (t < s) red[t] += red[t + s]; __syncthreads(); }
    double lap_sum = red[0];
    if (t == 0) {
        float s = 0.f;
        for (int bb = 0; bb < BATCH; bb++) {
            unsigned u = atomicOr(&nmib[bb], 0u);   // device-scope atomic read
            s += __uint_as_float(u);
        }
        s /= (float)BATCH;
        s = fminf(fmaxf(s, -1.f), 1.f);
        double mi_loss = -(double)s;
        double mind_mean = mind_sum / (64.0 * (double)PLANE_F);
        double reg = grad_sum / (double)(BATCH * PLANE_S) + lap_sum / (double)(BATCH * PLANE_S);
        out[0] = (float)(mi_loss + 5.0 * mind_mean + 0.1 * reg);
    }
}

extern "C" void kernel_launch(void* const* d_in, const int* in_sizes, int n_in,
                              void* d_out, int out_size, void* d_ws, size_t ws_size,
                              hipStream_t stream) {
    const float* fixed = (const float*)d_in[0];
    const float* moved = (const float*)d_in[1];
    const float* flow  = (const float*)d_in[2];
    float* out = (float*)d_out;
    char* ws = (char*)d_ws;

    unsigned* hist  = (unsigned*)(ws + OFF_HIST);
    unsigned* cnt   = (unsigned*)(ws + OFF_CNT);
    unsigned* nmib  = (unsigned*)(ws + OFF_NMIB);
    double*   pmind = (double*)(ws + OFF_PMIND);
    double*   pgrad = (double*)(ws + OFF_PGRAD);
    double*   plap  = (double*)(ws + OFF_PLAP);

    init_kernel<<<dim3(1), 256, 0, stream>>>(hist, cnt);
    // z-slices 0,1 = reg; z 2..9 = mind (b = z-2)
    fused_main_kernel<<<dim3(16, 16, 10), 256, 0, stream>>>(fixed, moved, flow,
                                                            hist, pmind, pgrad, plap);
    tail_kernel<<<dim3(BATCH), 256, 0, stream>>>(hist, cnt, nmib, pmind, pgrad, plap, out);
}

// Round 9
// 106.748 us; speedup vs baseline: 1.0335x; 1.0035x over previous
//
#include <hip/hip_runtime.h>
#include <cmath>

// Problem constants
#define BATCH 8
#define HF 512
#define WF 512
#define HS 256
#define WS 256
#define PLANE_S (HS * WS)   // 65536
#define PLANE_F (HF * WF)   // 262144

#define NMIND_BLOCKS 2048   // 16x16 tiles x 8 batches
#define NREG_BLOCKS  512    // 8x8 tiles x 8 batches

// Workspace layout (bytes).
// hist + cnt are atomically accumulated (zeroed by init_kernel);
// partial arrays are fully written before read (no init needed).
#define OFF_HIST  0                              // 8*256 u32 = 8 KB
#define OFF_CNT   (8 * 256 * 4)                  // 1 u32 ticket counter
#define OFF_NMIB  (OFF_CNT + 4)                  // 8 u32 (nmi bits, atomic transport)
#define OFF_PMIND 8704                           // 2048 doubles
#define OFF_PGRAD (OFF_PMIND + NMIND_BLOCKS * 8)
#define OFF_PLAP  (OFF_PGRAD + NREG_BLOCKS * 8)

// mega patch geometry for a 32x32 output tile
#define IMG_R 23   // pooled img patch rows/cols (V_R + 5 halo)
#define IMG_S 24   // LDS stride
#define T_R 20     // (img - offset-boxmean)^2 patch
#define T_S 21
#define V_R 18     // variance / diff patch
#define V_S 19
#define V_PLANE (V_R * V_S)   // 342; diff = 4 pair-planes of 342 float2

// reg patch geometry for a 32x32 pooled tile
#define RP 34
#define RS 35

__device__ __forceinline__ int clampi(int v, int lo, int hi) {
    return v < lo ? lo : (v > hi ? hi : v);
}

__device__ __forceinline__ int bin_of(float x) {
    float v = (x + 1.0f) * 0.5f;
    v = fminf(fmaxf(v, 0.001f), 0.999f);
    float t = v * 16.0f;            // exact (power-of-2 scale)
    float ft = floorf(t);
    int c = (int)ft + ((t > ft) ? 1 : 0);   // searchsorted-left count of grid < v
    int b = c - 1;
    return b < 0 ? 0 : (b > 15 ? 15 : b);
}

// zero the 8x256 global histogram + ticket counter (workspace is poisoned per iteration)
__global__ void init_kernel(unsigned* __restrict__ hist, unsigned* __restrict__ cnt) {
    int t = threadIdx.x;
    for (int i = t; i < BATCH * 256; i += 256) hist[i] = 0u;
    if (t == 0) cnt[0] = 0u;
}

// ONE kernel, two roles by blockIdx.z:
//   z in {0,1}  : reg path  — 512 blocks (8x8 pooled tiles x 8 batches)
//   z in 2..9   : mind path — 2048 blocks (16x16 output tiles x 8 batches), b = z-2
// LDS 20144 B (<=20480) -> 8 blocks/CU = 32 waves/CU.
// mega is LDS-PIPE-bound (R4-R8 evidence): upsample is quad-structured so a 2x2
// output quad shares one 3x3 input neighborhood -> 36 b64 reads/thread (was 64).
__global__ __launch_bounds__(256, 8) void fused_main_kernel(
    const float* __restrict__ fixed, const float* __restrict__ moved,
    const float* __restrict__ flow,
    unsigned* __restrict__ hist, double* __restrict__ pmind,
    double* __restrict__ pgrad, double* __restrict__ plap)
{
    __shared__ __align__(16) float S[4524];
    __shared__ unsigned lh[256];
    __shared__ float red[256];
    int tid = threadIdx.x;

    if (blockIdx.z < 2) {
        // ---------------- reg path: pool(flow) -> Sobel + Laplacian partial sums
        int idx = blockIdx.z * 256 + blockIdx.y * 16 + blockIdx.x;  // 0..511
        int b = idx >> 6, t64 = idx & 63;
        int y0p = (t64 >> 3) * 32, x0p = (t64 & 7) * 32;
        float* U = S;
        float* V = S + RP * RS;
        const float* ur = flow + (size_t)(b * 2) * PLANE_F;
        const float* vr = ur + PLANE_F;
        for (int i = tid; i < RP * RP; i += 256) {
            int r = i / RP, c = i - r * RP;
            int gy = clampi(y0p - 1 + r, 0, HS - 1);
            int gx = clampi(x0p - 1 + c, 0, WS - 1);
            const float* uu = ur + (size_t)(gy * 2) * WF + (size_t)(gx * 2);
            const float* vv = vr + (size_t)(gy * 2) * WF + (size_t)(gx * 2);
            float2 u0 = *(const float2*)uu, u1 = *(const float2*)(uu + WF);
            float2 v0 = *(const float2*)vv, v1 = *(const float2*)(vv + WF);
            U[r * RS + c] = (u0.x + u0.y + u1.x + u1.y) * 0.25f;
            V[r * RS + c] = (v0.x + v0.y + v1.x + v1.y) * 0.25f;
        }
        __syncthreads();
        float g = 0.f, l = 0.f;
        for (int k = tid; k < 32 * 32; k += 256) {
            int y = k >> 5, x = k & 31;
            const float* u0 = &U[y * RS + x];
            const float* v0 = &V[y * RS + x];
            float a00 = u0[0],      a01 = u0[1],          a02 = u0[2];
            float a10 = u0[RS],     a11 = u0[RS + 1],     a12 = u0[RS + 2];
            float a20 = u0[2 * RS], a21 = u0[2 * RS + 1], a22 = u0[2 * RS + 2];
            float c00 = v0[0],      c01 = v0[1],          c02 = v0[2];
            float c10 = v0[RS],     c11 = v0[RS + 1],     c12 = v0[RS + 2];
            float c20 = v0[2 * RS], c21 = v0[2 * RS + 1], c22 = v0[2 * RS + 2];
            float gxu = (a02 - a00) + 2.f * (a12 - a10) + (a22 - a20);
            float gyu = (a20 - a00) + 2.f * (a21 - a01) + (a22 - a02);
            float gxv = (c02 - c00) + 2.f * (c12 - c10) + (c22 - c20);
            float gyv = (c20 - c00) + 2.f * (c21 - c01) + (c22 - c02);
            float lpu = a01 + a10 - 4.f * a11 + a12 + a21;
            float lpv = c01 + c10 - 4.f * c11 + c12 + c21;
            float grad = gxu * gxu + gyu * gyu + gxv * gxv + gyv * gyv;
            float lap = lpu * lpu + lpv * lpv;
            g += fminf(grad, 100.f);
            l += fminf(lap, 100.f);
        }
        // combined wave-shuffle reduction for g and l: ONE barrier total
        #pragma unroll
        for (int off = 32; off; off >>= 1) {
            g += __shfl_down(g, off);
            l += __shfl_down(l, off);
        }
        if ((tid & 63) == 0) { red[tid >> 6] = g; red[4 + (tid >> 6)] = l; }
        __syncthreads();
        if (tid == 0) {
            pgrad[b * 64 + t64] = (double)(((red[0] + red[1]) + red[2]) + red[3]);
            plap[b * 64 + t64]  = (double)(((red[4] + red[5]) + red[6]) + red[7]);
        }
        return;
    }

    // ---------------- mind path: pool -> patchmean -> variance -> MIND -> diff ->
    // bilinear upsample -> sum|.| + joint histogram of the ::2,::2 raw samples.
    const float FS = (float)(255.0 / 511.0);
    int tx = blockIdx.x, ty = blockIdx.y, b = blockIdx.z - 2;
    int Xb = tx * 32, Yb = ty * 32;
    int dbx = (int)((float)Xb * FS);   // min x0 over the tile (fp32 multiply is monotone)
    int dby = (int)((float)Yb * FS);
    int ibx = dbx - 3, iby = dby - 3;  // pooled img patch base

    float* imgF = S;                        // 23*24 = 552
    float* imgM = S + IMG_R * IMG_S;        // 552
    float* varF = S + 2 * IMG_R * IMG_S;    // 18*19 = 342
    float* varM = varF + V_R * V_S;         // 342
    float* diff = varM + V_R * V_S;         // 2736 floats = 4 pair-planes x 342 float2
    // Aliases inside the (currently dead) diff region:
    float* tF   = diff;                     // 20*21 = 420
    float* tM   = diff + 420;               // 420
    float* rsF  = diff + 840;               // 22*20 = 440 (img row-sums)
    float* rsM  = diff + 1280;              // 440
    float* vsF  = diff + 840;               // 20*18 = 360 (t row-sums; rs dead)
    float* vsM  = diff + 1200;              // 360

    lh[tid] = 0u;
    __syncthreads();

    // ---- stage pooled F/M patches (clamp-at-staging = edge-pad semantics) + histogram
    const float* fb = fixed + (size_t)b * PLANE_F;
    const float* mb = moved + (size_t)b * PLANE_F;
    int oy0 = ty * 16, ox0 = tx * 16;   // owned pooled box for the histogram (exact cover)
    for (int i = tid; i < IMG_R * IMG_R; i += 256) {
        int r = i / IMG_R, c = i - r * IMG_R;
        int gy = iby + r, gx = ibx + c;
        int cy = clampi(gy, 0, HS - 1), cx = clampi(gx, 0, WS - 1);
        const float* fp = fb + (size_t)(cy * 2) * WF + (size_t)(cx * 2);
        const float* mp = mb + (size_t)(cy * 2) * WF + (size_t)(cx * 2);
        float2 f0 = *(const float2*)fp;
        float2 f1 = *(const float2*)(fp + WF);
        float2 m0 = *(const float2*)mp;
        float2 m1 = *(const float2*)(mp + WF);
        imgF[r * IMG_S + c] = (f0.x + f0.y + f1.x + f1.y) * 0.25f;
        imgM[r * IMG_S + c] = (m0.x + m0.y + m1.x + m1.y) * 0.25f;
        // ::2,::2 histogram sample = top-left raw pixel of the pool window
        if ((unsigned)(gy - oy0) < 16u && (unsigned)(gx - ox0) < 16u) {
            atomicAdd(&lh[bin_of(f0.x) * 16 + bin_of(m0.x)], 1u);
        }
    }
    __syncthreads();
    // accumulate non-zero bins into the per-batch global histogram (integer = exact)
    if (lh[tid]) atomicAdd(&hist[b * 256 + tid], lh[tid]);

    const float NINTH = 1.0f / 9.0f;

    // ---- 2a: img row-sums  rs[rr][c] = img[rr][c] + img[rr][c+1] + img[rr][c+2]
    for (int i = tid; i < 22 * 20; i += 256) {
        int rr = i / 20, c = i - rr * 20;
        const float* pF = &imgF[rr * IMG_S + c];
        const float* pM = &imgM[rr * IMG_S + c];
        rsF[i] = (pF[0] + pF[1]) + pF[2];
        rsM[i] = (pM[0] + pM[1]) + pM[2];
    }
    __syncthreads();

    // ---- 2b: t = (img[r+2][c+2] - boxmean)^2 via column sum of rs
    for (int i = tid; i < T_R * T_R; i += 256) {
        int r = i / T_R, c = i - r * T_R;
        float sF = (rsF[r * 20 + c] + rsF[(r + 1) * 20 + c]) + rsF[(r + 2) * 20 + c];
        float sM = (rsM[r * 20 + c] + rsM[(r + 1) * 20 + c]) + rsM[(r + 2) * 20 + c];
        float dF = imgF[(r + 2) * IMG_S + c + 2] - sF * NINTH;
        float dM = imgM[(r + 2) * IMG_S + c + 2] - sM * NINTH;
        tF[r * T_S + c] = dF * dF;
        tM[r * T_S + c] = dM * dM;
    }
    __syncthreads();

    // ---- 3a: t row-sums
    for (int i = tid; i < 20 * 18; i += 256) {
        int rr = i / 18, c = i - rr * 18;
        const float* pF = &tF[rr * T_S + c];
        const float* pM = &tM[rr * T_S + c];
        vsF[i] = (pF[0] + pF[1]) + pF[2];
        vsM[i] = (pM[0] + pM[1]) + pM[2];
    }
    __syncthreads();

    // ---- 3b: var = max(colsum(vs)/9, 1e-4)
    for (int i = tid; i < V_R * V_R; i += 256) {
        int r = i / V_R, c = i - r * V_R;
        float sF = (vsF[r * 18 + c] + vsF[(r + 1) * 18 + c]) + vsF[(r + 2) * 18 + c];
        float sM = (vsM[r * 18 + c] + vsM[(r + 1) * 18 + c]) + vsM[(r + 2) * 18 + c];
        varF[r * V_S + c] = fmaxf(sF * NINTH, 1e-4f);
        varM[r * V_S + c] = fmaxf(sM * NINTH, 1e-4f);
    }
    __syncthreads();

    // ---- MIND + diff (overwrites dead t/rs/vs), PAIR-PLANAR b64 writes
    float2* d2w = (float2*)diff;
    for (int i = tid; i < V_R * V_R; i += 256) {
        int r = i / V_R, c = i - r * V_R;
        float cF = imgF[(r + 3) * IMG_S + c + 3];
        float cM = imgM[(r + 3) * IMG_S + c + 3];
        float dF2 = 2.f * varF[r * V_S + c] + 1e-6f;
        float dM2 = 2.f * varM[r * V_S + c] + 1e-6f;
        float invF = 1.0f / dF2;           // hoisted reciprocal
        float invM = 1.0f / dM2;
        float eF[8], eM[8];
        float sF = 0.f, sM = 0.f;
        int ch = 0;
        #pragma unroll
        for (int ii = -1; ii <= 1; ii++) {
            #pragma unroll
            for (int jj = -1; jj <= 1; jj++) {
                if (ii == 0 && jj == 0) continue;
                float aF = cF - imgF[(r + 3 + 2 * jj) * IMG_S + (c + 3 + 2 * ii)];
                float aM = cM - imgM[(r + 3 + 2 * jj) * IMG_S + (c + 3 + 2 * ii)];
                float qF = fminf(aF * aF * invF, 50.f);
                float qM = fminf(aM * aM * invM, 50.f);
                float vF_ = __expf(-qF), vM_ = __expf(-qM);   // v_exp_f32 fast path
                eF[ch] = vF_; eM[ch] = vM_;
                sF += vF_; sM += vM_;
                ch++;
            }
        }
        float wF = 1.f / (sF + 1e-8f);
        float wM = 1.f / (sM + 1e-8f);
        int pix = r * V_S + c;
        #pragma unroll
        for (int q2 = 0; q2 < 4; q2++)
            d2w[q2 * V_PLANE + pix] = make_float2(eF[2 * q2] * wF - eM[2 * q2] * wM,
                                                  eF[2 * q2 + 1] * wF - eM[2 * q2 + 1] * wM);
    }
    __syncthreads();

    // ---- bilinear upsample + sum|.|: QUAD-structured. Thread owns output 2x2
    // quad (2qy..2qy+1, 2qx..2qx+1); its 4 bilinear taps lie in a 3x3 input
    // neighborhood (y0 of adjacent px differ by <=1). 9 float2 loads per
    // channel-pair = 36 b64 reads/thread (was 64). Zero-weight trick keeps the
    // per-px arithmetic bitwise identical (x + 0.0f == x; 0*v == +-0).
    float local = 0.f;
    const float2* d2 = (const float2*)diff;
    {
        int qy = tid >> 4, qx = tid & 15;
        // per-px coords — formulas identical to reference
        float py0 = (float)(Yb + 2 * qy) * FS;
        int ya = (int)py0; if (ya > HS - 2) ya = HS - 2;
        float fy0 = py0 - (float)ya;
        float py1 = (float)(Yb + 2 * qy + 1) * FS;
        int yb = (int)py1; if (yb > HS - 2) yb = HS - 2;
        float fy1 = py1 - (float)yb;
        float px0 = (float)(Xb + 2 * qx) * FS;
        int xa = (int)px0; if (xa > WS - 2) xa = WS - 2;
        float fx0 = px0 - (float)xa;
        float px1 = (float)(Xb + 2 * qx + 1) * FS;
        int xb = (int)px1; if (xb > WS - 2) xb = WS - 2;
        float fx1 = px1 - (float)xb;
        int dyb = yb - ya;   // 0 or 1
        int dxb = xb - xa;   // 0 or 1
        // row weights: top px uses rows (0,1); bottom px uses (dyb?1,2:0,1)
        float wy0a = 1.f - fy0, wy1a = 1.f - fy1;
        float wr0b = dyb ? 0.f : wy1a;
        float wr1b = dyb ? wy1a : fy1;
        float wr2b = dyb ? fy1 : 0.f;
        // col weights: left px uses cols (0,1); right px uses (dxb?1,2:0,1)
        float wx0a = 1.f - fx0, wx1a = 1.f - fx1;
        float wc0r = dxb ? 0.f : wx1a;
        float wc1r = dxb ? wx1a : fx1;
        float wc2r = dxb ? fx1 : 0.f;
        int base = (ya - dby) * V_S + (xa - dbx);
        #pragma unroll
        for (int q2 = 0; q2 < 4; q2++) {
            const float2* dp = d2 + q2 * V_PLANE + base;
            float2 r0c0 = dp[0],         r0c1 = dp[1],             r0c2 = dp[2];
            float2 r1c0 = dp[V_S],       r1c1 = dp[V_S + 1],       r1c2 = dp[V_S + 2];
            float2 r2c0 = dp[2 * V_S],   r2c1 = dp[2 * V_S + 1],   r2c2 = dp[2 * V_S + 2];
            // top row-interps (rows 0,1) at 3 cols
            float t0x = r0c0.x * wy0a + r1c0.x * fy0, t0y = r0c0.y * wy0a + r1c0.y * fy0;
            float t1x = r0c1.x * wy0a + r1c1.x * fy0, t1y = r0c1.y * wy0a + r1c1.y * fy0;
            float t2x = r0c2.x * wy0a + r1c2.x * fy0, t2y = r0c2.y * wy0a + r1c2.y * fy0;
            // bottom row-interps (zero-weight select over rows 0..2)
            float b0x = (r0c0.x * wr0b + r1c0.x * wr1b) + r2c0.x * wr2b;
            float b0y = (r0c0.y * wr0b + r1c0.y * wr1b) + r2c0.y * wr2b;
            float b1x = (r0c1.x * wr0b + r1c1.x * wr1b) + r2c1.x * wr2b;
            float b1y = (r0c1.y * wr0b + r1c1.y * wr1b) + r2c1.y * wr2b;
            float b2x = (r0c2.x * wr0b + r1c2.x * wr1b) + r2c2.x * wr2b;
            float b2y = (r0c2.y * wr0b + r1c2.y * wr1b) + r2c2.y * wr2b;
            // 4 px: col-interp (left: cols 0,1; right: zero-weight over 0..2)
            local += fabsf(t0x * wx0a + t1x * fx0);
            local += fabsf(t0y * wx0a + t1y * fx0);
            local += fabsf((t0x * wc0r + t1x * wc1r) + t2x * wc2r);
            local += fabsf((t0y * wc0r + t1y * wc1r) + t2y * wc2r);
            local += fabsf(b0x * wx0a + b1x * fx0);
            local += fabsf(b0y * wx0a + b1y * fx0);
            local += fabsf((b0x * wc0r + b1x * wc1r) + b2x * wc2r);
            local += fabsf((b0y * wc0r + b1y * wc1r) + b2y * wc2r);
        }
    }
    // wave-shuffle reduction: 1 barrier instead of 8
    #pragma unroll
    for (int off = 32; off; off >>= 1) local += __shfl_down(local, off);
    if ((tid & 63) == 0) red[tid >> 6] = local;
    __syncthreads();
    if (tid == 0)
        pmind[b * 256 + ty * 16 + tx] = (double)(((red[0] + red[1]) + red[2]) + red[3]);
}

// 8 parallel blocks: block b computes nmi(b) from the tiny 256-bin histogram and
// publishes it via device-scope atomics; the LAST finishing block (ticket) also
// runs the final partial-sum reduction.
__global__ void tail_kernel(const unsigned* __restrict__ hist,
                            unsigned* __restrict__ cnt, unsigned* __restrict__ nmib,
                            const double* __restrict__ pmind,
                            const double* __restrict__ pgrad, const double* __restrict__ plap,
                            float* __restrict__ out) {
    int b = blockIdx.x;
    int t = threadIdx.x;  // 256
    __shared__ float p[256];
    __shared__ float xh[16], yh[16];
    __shared__ float redf[256];
    __shared__ double red[256];
    __shared__ unsigned ticket;

    // ---- nmi(b): one load per thread, then LDS reductions
    unsigned hv = hist[b * 256 + t];
    float pv = (float)hv / 65536.0f;  // sum+1e-10 == 65536 in fp32
    p[t] = pv;
    __syncthreads();
    if (t < 16) {
        float s = 0.f;
        for (int j = 0; j < 16; j++) s += p[t * 16 + j];
        xh[t] = s;
    } else if (t < 32) {
        int j = t - 16;
        float s = 0.f;
        for (int i = 0; i < 16; i++) s += p[i * 16 + j];
        yh[j] = s;
    }
    __syncthreads();
    const float eps = 1e-5f;
    int i = t >> 4, j = t & 15;
    float h = pv + eps;
    float mi_term = h * (logf(h) - logf((xh[i] + eps) * (yh[j] + eps)));
    redf[t] = mi_term;
    __syncthreads();
    for (int s = 128; s > 0; s >>= 1) { if (t < s) redf[t] += redf[t + s]; __syncthreads(); }
    float mi = redf[0];
    __syncthreads();
    float e_term = 0.f;
    if (t < 16) { float xe = xh[t] + eps; e_term = -xe * logf(xe); }
    else if (t < 32) { float ye = yh[t - 16] + eps; e_term = -ye * logf(ye); }
    redf[t] = e_term;
    __syncthreads();
    for (int s = 128; s > 0; s >>= 1) { if (t < s) redf[t] += redf[t + s]; __syncthreads(); }
    if (t == 0) {
        float se = redf[0];  // hx + hy
        float nmi = (se < 1e-10f) ? 0.f : 2.f * mi / se;
        nmi = fminf(fmaxf(nmi, -1.f), 1.f);
        atomicExch(&nmib[b], __float_as_uint(nmi));
        ticket = atomicAdd(cnt, 1u);
    }
    __syncthreads();
    if (ticket != BATCH - 1) return;

    // ---- last block: final reduction over all partials (written by the previous
    // kernel -> visible across the kernel boundary; nmi values read via atomics)
    double sm = 0.0;
    for (int i2 = t; i2 < NMIND_BLOCKS; i2 += 256) sm += pmind[i2];
    double sg = 0.0, sl = 0.0;
    for (int i2 = t; i2 < NREG_BLOCKS; i2 += 256) { sg += pgrad[i2]; sl += plap[i2]; }
    red[t] = sm;
    __syncthreads();
    for (int s = 128; s > 0; s >>= 1) { if (t < s) red[t] += red[t + s]; __syncthreads(); }
    double mind_sum = red[0];
    __syncthreads();
    red[t] = sg;
    __syncthreads();
    for (int s = 128; s > 0; s >>= 1) { if (t < s) red[t] += red[t + s]; __syncthreads(); }
    double grad_sum = red[0];
    __syncthreads();
    red[t] = sl;
    __syncthreads();
    for (int s = 128; s > 0; s >>= 1) { if (t < s) red[t] += red[t + s]; __syncthreads(); }
    double lap_sum = red[0];
    if (t == 0) {
        float s = 0.f;
        for (int bb = 0; bb < BATCH; bb++) {
            unsigned u = atomicOr(&nmib[bb], 0u);   // device-scope atomic read
            s += __uint_as_float(u);
        }
        s /= (float)BATCH;
        s = fminf(fmaxf(s, -1.f), 1.f);
        double mi_loss = -(double)s;
        double mind_mean = mind_sum / (64.0 * (double)PLANE_F);
        double reg = grad_sum / (double)(BATCH * PLANE_S) + lap_sum / (double)(BATCH * PLANE_S);
        out[0] = (float)(mi_loss + 5.0 * mind_mean + 0.1 * reg);
    }
}

extern "C" void kernel_launch(void* const* d_in, const int* in_sizes, int n_in,
                              void* d_out, int out_size, void* d_ws, size_t ws_size,
                              hipStream_t stream) {
    const float* fixed = (const float*)d_in[0];
    const float* moved = (const float*)d_in[1];
    const float* flow  = (const float*)d_in[2];
    float* out = (float*)d_out;
    char* ws = (char*)d_ws;

    unsigned* hist  = (unsigned*)(ws + OFF_HIST);
    unsigned* cnt   = (unsigned*)(ws + OFF_CNT);
    unsigned* nmib  = (unsigned*)(ws + OFF_NMIB);
    double*   pmind = (double*)(ws + OFF_PMIND);
    double*   pgrad = (double*)(ws + OFF_PGRAD);
    double*   plap  = (double*)(ws + OFF_PLAP);

    init_kernel<<<dim3(1), 256, 0, stream>>>(hist, cnt);
    // z-slices 0,1 = reg; z 2..9 = mind (b = z-2)
    fused_main_kernel<<<dim3(16, 16, 10), 256, 0, stream>>>(fixed, moved, flow,
                                                            hist, pmind, pgrad, plap);
    tail_kernel<<<dim3(BATCH), 256, 0, stream>>>(hist, cnt, nmib, pmind, pgrad, plap, out);
}